// Round 4
// baseline (118.182 us; speedup 1.0000x reference)
//
#include <hip/hip_runtime.h>

// Problem constants (B=1 fixed by reference)
#define HW_TOTAL (480 * 640)           // 307200 pixels
#define NC 12                           // output channels (C-1)
#define VOX_TOTAL_C (240 * 144 * 240)   // 8,294,400 voxels (divisible by 16)

#define TRANS_BLOCKS (HW_TOTAL / 256)   // 1200
#define ZERO_BLOCKS  1536
#define PREP_BLOCKS  (TRANS_BLOCKS + ZERO_BLOCKS)

typedef float f32x4 __attribute__((ext_vector_type(4)));
typedef int   i32x4 __attribute__((ext_vector_type(4)));

// k1 "prep": heterogeneous blocks.
//  - blocks [0, TRANS_BLOCKS): transpose x (13, HW) -> xT (HW, 12), channels 1..12,
//    LDS-staged so global reads and writes are coalesced. xT stays cacheable (L2/L3)
//    for the gather's random reads.
//  - blocks [TRANS_BLOCKS, PREP_BLOCKS): grid-stride zero of inv (nontemporal).
__global__ void prep_kernel(const float* __restrict__ x,
                            float* __restrict__ xT,
                            int* __restrict__ inv) {
    __shared__ float lds[256 * 13];   // pad 12->13 to break bank conflicts
    const int tid = threadIdx.x;
    const int b = blockIdx.x;
    if (b < TRANS_BLOCKS) {
        const int p0 = b * 256;
#pragma unroll
        for (int c = 0; c < NC; ++c)
            lds[tid * 13 + c] = x[(size_t)(c + 1) * HW_TOTAL + p0 + tid];
        __syncthreads();
        float* dst = xT + (size_t)p0 * NC;
#pragma unroll
        for (int it = 0; it < NC; ++it) {
            int j = it * 256 + tid;
            dst[j] = lds[(j / NC) * 13 + (j % NC)];
        }
    } else {
        const int t0 = (b - TRANS_BLOCKS) * 256 + tid;
        const int stride = ZERO_BLOCKS * 256;
        const i32x4 z = {0, 0, 0, 0};
        for (int i = t0; i < VOX_TOTAL_C / 4; i += stride)
            __builtin_nontemporal_store(z, (i32x4*)inv + i);
    }
}

// k2: scatter pixel index into inverse map (inv pre-zeroed; p+1, 0 = empty).
// Map values are a permutation -> no write conflicts.
__global__ void build_inv_kernel(const int* __restrict__ map,
                                 int* __restrict__ inv) {
    int p = blockIdx.x * blockDim.x + threadIdx.x;
    if (p >= HW_TOTAL) return;
    int v = map[p];
    if (v > 0) inv[v] = p + 1;   // v==0 means invalid pixel (dropped)
}

// k3: streaming gather, branchless. 4 voxels/thread. Every lane always loads a
// 48-B xT record (clamped address) and zeroes via 0/1 multiply -> no exec-mask
// divergence, all 13 loads issue back-to-back for max MLP. inv read + out
// write nontemporal to keep L2 for xT.
__global__ void gather_kernel(const float* __restrict__ xT,
                              const int* __restrict__ inv,
                              float* __restrict__ out) {
    int t = blockIdx.x * blockDim.x + threadIdx.x;
    if (t >= VOX_TOTAL_C / 4) return;
    i32x4 pv = __builtin_nontemporal_load((const i32x4*)inv + t);
    f32x4 A[4][3];
    float m[4];
#pragma unroll
    for (int k = 0; k < 4; ++k) {
        int p = pv[k];
        int q = (p > 0) ? (p - 1) : 0;          // always-valid address
        const f32x4* r = (const f32x4*)(xT + (size_t)q * NC);
        A[k][0] = r[0];
        A[k][1] = r[1];
        A[k][2] = r[2];
        m[k] = (p > 0) ? 1.0f : 0.0f;
    }
    size_t base = (size_t)t * 4;
#pragma unroll
    for (int c = 0; c < NC; ++c) {
        f32x4 o = { A[0][c >> 2][c & 3] * m[0],
                    A[1][c >> 2][c & 3] * m[1],
                    A[2][c >> 2][c & 3] * m[2],
                    A[3][c >> 2][c & 3] * m[3] };
        __builtin_nontemporal_store(o, (f32x4*)(out + (size_t)c * VOX_TOTAL_C + base));
    }
}

extern "C" void kernel_launch(void* const* d_in, const int* in_sizes, int n_in,
                              void* d_out, int out_size, void* d_ws, size_t ws_size,
                              hipStream_t stream) {
    const float* x = (const float*)d_in[0];      // (1, 13, 480, 640) f32
    const int* map = (const int*)d_in[1];        // (1, 307200) i32
    float* out = (float*)d_out;                  // (1, 12, 240, 144, 240) f32

    int*   inv = (int*)d_ws;                            // 33.2 MB
    float* xT  = (float*)((char*)d_ws +
                          (size_t)VOX_TOTAL_C * sizeof(int));  // 14.7 MB

    // k1: transpose || zero-inv (replaces hipMemsetAsync + transpose launches)
    prep_kernel<<<PREP_BLOCKS, 256, 0, stream>>>(x, xT, inv);

    // k2: build inverse map
    build_inv_kernel<<<HW_TOTAL / 256, 256, 0, stream>>>(map, inv);

    // k3: gather: 2,073,600 threads
    const int total = VOX_TOTAL_C / 4;
    gather_kernel<<<(total + 255) / 256, 256, 0, stream>>>(xT, inv, out);
}